// Round 1
// baseline (215.743 us; speedup 1.0000x reference)
//
#include <hip/hip_runtime.h>
#include <hip/hip_bf16.h>

// Problem constants (reference: B=2, S=2048, D=1024, H=16, HD=64)
constexpr int Bb = 2, Ss = 2048, Dd = 1024, Hh = 16, HD = 64;
constexpr int Mrows = Bb * Ss;                 // 4096 rows for projections
constexpr float SCALE = 0.125f;                // 1/sqrt(HD)
constexpr size_t CTX_ELEMS = (size_t)Bb * Hh * Ss * HD;  // 4194304

typedef __attribute__((ext_vector_type(8))) short   short8;
typedef __attribute__((ext_vector_type(4))) float   floatx4;
typedef __attribute__((ext_vector_type(8))) __bf16  bf16x8;

#define DEVI __device__ __forceinline__

DEVI unsigned short f2bf(float f) {
  union { float f; unsigned u; } x; x.f = f;
  unsigned r = (x.u + 0x7fffu + ((x.u >> 16) & 1u)) >> 16;   // RNE
  return (unsigned short)r;
}

// ---------------------------------------------------------------------------
// Kernel 1: QKV projection.  Y = X @ W^T + bias, output bf16 in [B,H,S,HD].
// Tile 128x128, BK=32, 4 waves (each 64x64 via 4x4 frags of 16x16x32 MFMA).
// LDS rows padded to 40 shorts (80B): 16B-aligned b128 reads, ~2-way banks.
// ---------------------------------------------------------------------------
constexpr int BM = 128, BN = 128, BK = 32;
constexpr int APAD = 40;   // shorts per LDS row (32 data + 8 pad)

__global__ __launch_bounds__(256, 2) void qkv_proj(
    const float* __restrict__ Xq, const float* __restrict__ Xk, const float* __restrict__ Xv,
    const float* __restrict__ Wq, const float* __restrict__ Wk, const float* __restrict__ Wv,
    const float* __restrict__ bq, const float* __restrict__ bk, const float* __restrict__ bv,
    unsigned short* __restrict__ ws)
{
  const int sel = blockIdx.y;
  const float* X    = sel == 0 ? Xq : sel == 1 ? Xk : Xv;
  const float* W    = sel == 0 ? Wq : sel == 1 ? Wk : Wv;
  const float* bias = sel == 0 ? bq : sel == 1 ? bk : bv;
  unsigned short* out = ws + (size_t)sel * ((size_t)Mrows * Dd);

  __shared__ __align__(16) unsigned short As[BM * APAD];
  __shared__ __align__(16) unsigned short Bs[BN * APAD];

  const int t    = threadIdx.x;
  const int bm   = blockIdx.x >> 3;      // 32 m-blocks
  const int bn   = blockIdx.x & 7;       // 8 n-blocks
  const int wid  = t >> 6, lane = t & 63;
  const int lrow = lane & 15, lg = lane >> 4;
  const int wm   = (wid >> 1) * 64, wn = (wid & 1) * 64;

  floatx4 acc[4][4];
  #pragma unroll
  for (int i = 0; i < 4; ++i)
    #pragma unroll
    for (int j = 0; j < 4; ++j) acc[i][j] = 0.0f;

  for (int k0 = 0; k0 < Dd; k0 += BK) {
    __syncthreads();   // previous iteration's reads done before overwrite
    #pragma unroll
    for (int half = 0; half < 2; ++half) {
      const int cidx = t + half * 256;       // 0..511 chunks (8 fp32 each)
      const int r = cidx >> 2, c = cidx & 3;
      // A tile: X rows
      {
        const float* ga = X + (size_t)(bm * BM + r) * Dd + k0 + c * 8;
        const floatx4 x0 = *(const floatx4*)ga;
        const floatx4 x1 = *(const floatx4*)(ga + 4);
        short8 va;
        #pragma unroll
        for (int j = 0; j < 4; ++j) {
          va[j]     = (short)f2bf(x0[j]);
          va[4 + j] = (short)f2bf(x1[j]);
        }
        *(short8*)&As[r * APAD + c * 8] = va;
      }
      // B tile: W rows (output columns)
      {
        const float* gb = W + (size_t)(bn * BN + r) * Dd + k0 + c * 8;
        const floatx4 x0 = *(const floatx4*)gb;
        const floatx4 x1 = *(const floatx4*)(gb + 4);
        short8 vb;
        #pragma unroll
        for (int j = 0; j < 4; ++j) {
          vb[j]     = (short)f2bf(x0[j]);
          vb[4 + j] = (short)f2bf(x1[j]);
        }
        *(short8*)&Bs[r * APAD + c * 8] = vb;
      }
    }
    __syncthreads();

    bf16x8 af[4], bff[4];
    #pragma unroll
    for (int mi = 0; mi < 4; ++mi)
      af[mi] = __builtin_bit_cast(bf16x8, *(const short8*)&As[(wm + mi * 16 + lrow) * APAD + lg * 8]);
    #pragma unroll
    for (int ni = 0; ni < 4; ++ni)
      bff[ni] = __builtin_bit_cast(bf16x8, *(const short8*)&Bs[(wn + ni * 16 + lrow) * APAD + lg * 8]);

    #pragma unroll
    for (int mi = 0; mi < 4; ++mi)
      #pragma unroll
      for (int ni = 0; ni < 4; ++ni)
        acc[mi][ni] = __builtin_amdgcn_mfma_f32_16x16x32_bf16(af[mi], bff[ni], acc[mi][ni], 0, 0, 0);
  }

  // Epilogue: bias add, store bf16 into [B,H,S,HD]
  #pragma unroll
  for (int ni = 0; ni < 4; ++ni) {
    const int gcol = bn * BN + wn + ni * 16 + lrow;
    const float bval = bias[gcol];
    const int h = gcol >> 6, hd = gcol & 63;
    #pragma unroll
    for (int mi = 0; mi < 4; ++mi) {
      #pragma unroll
      for (int r = 0; r < 4; ++r) {
        const int grow = bm * BM + wm + mi * 16 + lg * 4 + r;   // = b*S + s
        const int b = grow >> 11, s = grow & 2047;
        out[(((size_t)(b * Hh + h) * Ss + s) << 6) + hd] = f2bf(acc[mi][ni][r] + bval);
      }
    }
  }
}

// ---------------------------------------------------------------------------
// Kernel 2: flash attention. Block = (b,h, 64 q-rows), 4 waves x 16 q-rows.
// K staged linear (padded), V staged transposed (padded), P via per-wave LDS.
// Writes context [B,H,S,HD] (fp32) and attn_output [B,S,D] (fp32).
// ---------------------------------------------------------------------------
constexpr int KPAD = 72;   // shorts per 64-wide LDS row (64 data + 8 pad)

__global__ __launch_bounds__(256, 2) void attn_fwd(
    const unsigned short* __restrict__ ws, float* __restrict__ out)
{
  __shared__ __align__(16) unsigned short Ks[64 * KPAD];
  __shared__ __align__(16) unsigned short Vt[64 * KPAD];       // transposed: [hd][kv]
  __shared__ __align__(16) unsigned short Pw[4][16 * KPAD];    // per-wave P tile

  const int t = threadIdx.x, wid = t >> 6, lane = t & 63;
  const int lrow = lane & 15, lg = lane >> 4;
  const int bh = blockIdx.y;                 // b*H + h
  const int b = bh >> 4, h = bh & 15;
  const unsigned short* Qb = ws + (size_t)bh * (Ss * HD);
  const unsigned short* Kb = Qb + (size_t)Mrows * Dd;
  const unsigned short* Vb = Kb + (size_t)Mrows * Dd;
  const int q0 = blockIdx.x * 64 + wid * 16;

  // Q fragments held in registers for the whole kernel
  bf16x8 qf[2];
  #pragma unroll
  for (int kf = 0; kf < 2; ++kf)
    qf[kf] = __builtin_bit_cast(bf16x8, *(const short8*)(Qb + (size_t)(q0 + lrow) * 64 + kf * 32 + lg * 8));

  floatx4 ctx[4];
  #pragma unroll
  for (int ni = 0; ni < 4; ++ni) ctx[ni] = 0.0f;
  float m_run[4], l_run[4];
  #pragma unroll
  for (int r = 0; r < 4; ++r) { m_run[r] = -1e30f; l_run[r] = 0.0f; }

  const int sr = t >> 2, sc = t & 3;   // staging: row 0..63, chunk-pair

  for (int kv0 = 0; kv0 < Ss; kv0 += 64) {
    __syncthreads();
    // ---- stage K (linear) and V (transposed) ----
    #pragma unroll
    for (int hf = 0; hf < 2; ++hf) {
      const int c = sc + hf * 4;     // chunk 0..7 (8 bf16 each)
      const short8 kk = *(const short8*)(Kb + (size_t)(kv0 + sr) * 64 + c * 8);
      *(short8*)&Ks[sr * KPAD + c * 8] = kk;
      const short8 vv = *(const short8*)(Vb + (size_t)(kv0 + sr) * 64 + c * 8);
      #pragma unroll
      for (int j = 0; j < 8; ++j)
        Vt[(c * 8 + j) * KPAD + sr] = (unsigned short)vv[j];
    }
    __syncthreads();

    // ---- S = Q K^T (rows=q, cols=kv) ----
    floatx4 s4[4];
    #pragma unroll
    for (int ni = 0; ni < 4; ++ni) s4[ni] = 0.0f;
    #pragma unroll
    for (int ni = 0; ni < 4; ++ni)
      #pragma unroll
      for (int kf = 0; kf < 2; ++kf) {
        const bf16x8 kfrag = __builtin_bit_cast(bf16x8,
            *(const short8*)&Ks[(ni * 16 + lrow) * KPAD + kf * 32 + lg * 8]);
        s4[ni] = __builtin_amdgcn_mfma_f32_16x16x32_bf16(qf[kf], kfrag, s4[ni], 0, 0, 0);
      }

    // ---- online softmax (row r lives in lanes sharing lg; cols across lrow) ----
    float mx[4];
    #pragma unroll
    for (int r = 0; r < 4; ++r)
      mx[r] = fmaxf(fmaxf(s4[0][r], s4[1][r]), fmaxf(s4[2][r], s4[3][r]));
    #pragma unroll
    for (int mask = 1; mask <= 8; mask <<= 1)
      #pragma unroll
      for (int r = 0; r < 4; ++r) mx[r] = fmaxf(mx[r], __shfl_xor(mx[r], mask));

    float alpha[4], psum[4];
    #pragma unroll
    for (int r = 0; r < 4; ++r) {
      const float mn = fmaxf(m_run[r], mx[r] * SCALE);
      alpha[r] = __expf(m_run[r] - mn);
      m_run[r] = mn;
      psum[r] = 0.0f;
    }
    #pragma unroll
    for (int ni = 0; ni < 4; ++ni)
      #pragma unroll
      for (int r = 0; r < 4; ++r) {
        const float p = __expf(s4[ni][r] * SCALE - m_run[r]);
        psum[r] += p;
        Pw[wid][(lg * 4 + r) * KPAD + ni * 16 + lrow] = f2bf(p);
      }
    #pragma unroll
    for (int mask = 1; mask <= 8; mask <<= 1)
      #pragma unroll
      for (int r = 0; r < 4; ++r) psum[r] += __shfl_xor(psum[r], mask);
    #pragma unroll
    for (int r = 0; r < 4; ++r) l_run[r] = l_run[r] * alpha[r] + psum[r];
    #pragma unroll
    for (int ni = 0; ni < 4; ++ni)
      #pragma unroll
      for (int r = 0; r < 4; ++r) ctx[ni][r] *= alpha[r];

    // ---- ctx += P V  (per-wave LDS P, DS ops in-order within a wave) ----
    #pragma unroll
    for (int kvs = 0; kvs < 2; ++kvs) {
      const bf16x8 pa = __builtin_bit_cast(bf16x8,
          *(const short8*)&Pw[wid][lrow * KPAD + kvs * 32 + lg * 8]);
      #pragma unroll
      for (int ni = 0; ni < 4; ++ni) {
        const bf16x8 vf = __builtin_bit_cast(bf16x8,
            *(const short8*)&Vt[(ni * 16 + lrow) * KPAD + kvs * 32 + lg * 8]);
        ctx[ni] = __builtin_amdgcn_mfma_f32_16x16x32_bf16(pa, vf, ctx[ni], 0, 0, 0);
      }
    }
  }

  // ---- epilogue: normalize, write both outputs ----
  float inv[4];
  #pragma unroll
  for (int r = 0; r < 4; ++r) inv[r] = 1.0f / l_run[r];
  #pragma unroll
  for (int ni = 0; ni < 4; ++ni) {
    const int hd = ni * 16 + lrow;
    #pragma unroll
    for (int r = 0; r < 4; ++r) {
      const int q = q0 + lg * 4 + r;
      const float val = ctx[ni][r] * inv[r];
      out[((size_t)bh * Ss + q) * 64 + hd] = val;                             // context [B,H,S,HD]
      out[CTX_ELEMS + (((size_t)(b * Ss + q)) << 10) + (h << 6) + hd] = val;  // attn_output [B,S,D]
    }
  }
}

// ---------------------------------------------------------------------------
extern "C" void kernel_launch(void* const* d_in, const int* in_sizes, int n_in,
                              void* d_out, int out_size, void* d_ws, size_t ws_size,
                              hipStream_t stream) {
  const float* q  = (const float*)d_in[0];
  const float* k  = (const float*)d_in[1];
  const float* v  = (const float*)d_in[2];
  const float* wq = (const float*)d_in[3];
  const float* bq = (const float*)d_in[4];
  const float* wk = (const float*)d_in[5];
  const float* bk = (const float*)d_in[6];
  const float* wv = (const float*)d_in[7];
  const float* bv = (const float*)d_in[8];
  unsigned short* ws = (unsigned short*)d_ws;   // 3 * 4096*1024 bf16 = 24 MB
  float* out = (float*)d_out;

  // Q,K,V projections -> bf16 [B,H,S,HD] in workspace
  qkv_proj<<<dim3(256, 3), 256, 0, stream>>>(q, k, v, wq, wk, wv, bq, bk, bv, ws);
  // Flash attention -> context + attn_output
  attn_fwd<<<dim3(Ss / 64, Bb * Hh), 256, 0, stream>>>(ws, out);
}